// Round 6
// baseline (290.370 us; speedup 1.0000x reference)
//
#include <hip/hip_runtime.h>

#define N_NODES 100000
#define N_EDGES 1600000
#define DIM 64

#define SCAN_BLK 2048
#define NSCAN ((N_NODES + 1 + SCAN_BLK - 1) / SCAN_BLK)   // 49 blocks

#define NSLICE 8
#define SLICE_NODES ((N_NODES + NSLICE - 1) / NSLICE)     // 12500 nodes/slice

// ===========================================================================
// Prologue: zero -> sliced hist -> scan1/2/3 -> sliced scatter-sort
// ===========================================================================

__global__ void zero_u32(unsigned* __restrict__ p, int n) {
    int i = blockIdx.x * blockDim.x + threadIdx.x;
    if (i < n) p[i] = 0u;
}

// XCD-sliced per-node histogram: block handles dst-slice (bid%8) over edge
// chunk (bid/8); counter cachelines stay resident in one XCD's L2.
__global__ void hist_kernel(const int* __restrict__ dst, unsigned* __restrict__ cnt) {
    int slice = blockIdx.x & (NSLICE - 1);
    int chunk = blockIdx.x >> 3;
    int nchunks = gridDim.x >> 3;
    int lo = slice * SLICE_NODES;
    int hi = lo + SLICE_NODES; if (hi > N_NODES) hi = N_NODES;
    int per = (N_EDGES + nchunks - 1) / nchunks;
    int e0 = chunk * per;
    int e1 = e0 + per; if (e1 > N_EDGES) e1 = N_EDGES;
    for (int e = e0 + threadIdx.x; e < e1; e += blockDim.x) {
        int d = dst[e];
        if (d >= lo && d < hi) atomicAdd(&cnt[d], 1u);
    }
}

// Block-local inclusive scan (2048/block) -> exclusive within block + partials.
__global__ void scan1_kernel(const unsigned* __restrict__ cnt,
                             unsigned* __restrict__ off,
                             unsigned* __restrict__ partials) {
    __shared__ unsigned s[SCAN_BLK];
    int t = threadIdx.x;
    int base = blockIdx.x * SCAN_BLK;
    int i0 = base + t, i1 = base + t + 1024;
    s[t]        = (i0 < N_NODES) ? cnt[i0] : 0u;
    s[t + 1024] = (i1 < N_NODES) ? cnt[i1] : 0u;
    __syncthreads();
    for (int o = 1; o < SCAN_BLK; o <<= 1) {
        unsigned a0 = s[t];
        unsigned a1 = s[t + 1024];
        unsigned b0 = (t >= o) ? s[t - o] : 0u;
        unsigned b1 = (t + 1024 >= o) ? s[t + 1024 - o] : 0u;
        __syncthreads();
        s[t] = a0 + b0;
        s[t + 1024] = a1 + b1;
        __syncthreads();
    }
    for (int i = t; i < SCAN_BLK; i += 1024) {
        int g = base + i;
        if (g <= N_NODES) off[g] = (i == 0) ? 0u : s[i - 1];
    }
    if (t == 0) partials[blockIdx.x] = s[SCAN_BLK - 1];
}

// Wave-parallel exclusive scan of the 49 block partials (was serial chain).
__global__ void scan2_kernel(unsigned* __restrict__ partials) {
    int t = threadIdx.x;   // 64 threads
    unsigned v = (t < NSCAN) ? partials[t] : 0u;
    unsigned orig = v;
    for (int o = 1; o < 64; o <<= 1) {
        unsigned n = __shfl_up(v, o, 64);
        if (t >= o) v += n;
    }
    if (t < NSCAN) partials[t] = v - orig;
}

// Add block offsets; init cursor = off.
__global__ void scan3_kernel(unsigned* __restrict__ off,
                             const unsigned* __restrict__ partials,
                             unsigned* __restrict__ cursor) {
    int i = blockIdx.x * blockDim.x + threadIdx.x;
    if (i <= N_NODES) {
        unsigned v = off[i] + partials[i / SCAN_BLK];
        off[i] = v;
        if (i < N_NODES) cursor[i] = v;
    }
}

// XCD-sliced scatter: cursor atomics + srt writes stay inside one XCD's L2.
__global__ void scatter_sort_kernel(const int* __restrict__ src,
                                    const int* __restrict__ dst,
                                    const float* __restrict__ w,
                                    unsigned* __restrict__ cursor,
                                    uint2* __restrict__ srt) {
    int slice = blockIdx.x & (NSLICE - 1);
    int chunk = blockIdx.x >> 3;
    int nchunks = gridDim.x >> 3;
    int lo = slice * SLICE_NODES;
    int hi = lo + SLICE_NODES; if (hi > N_NODES) hi = N_NODES;
    int per = (N_EDGES + nchunks - 1) / nchunks;
    int e0 = chunk * per;
    int e1 = e0 + per; if (e1 > N_EDGES) e1 = N_EDGES;
    for (int e = e0 + threadIdx.x; e < e1; e += blockDim.x) {
        int d = dst[e];
        if (d >= lo && d < hi) {
            unsigned pos = atomicAdd(&cursor[d], 1u);
            srt[pos] = make_uint2((unsigned)src[e], __float_as_uint(w[e]));
        }
    }
}

// ===========================================================================
// g = feat @ W   (streaming, perfectly pipelined; W in LDS, 2-way banks free)
// ===========================================================================
__global__ __launch_bounds__(256) void gemm_g_kernel(const float* __restrict__ feat,
                                                     const float* __restrict__ W,
                                                     float* __restrict__ g) {
    __shared__ float Ws[DIM * DIM];
    for (int i = threadIdx.x; i < DIM * DIM; i += 256) Ws[i] = W[i];
    __syncthreads();
    int lane = threadIdx.x & 63;
    int gwave = (int)((blockIdx.x * blockDim.x + threadIdx.x) >> 6);
    int nwaves = (int)((gridDim.x * blockDim.x) >> 6);
    for (int v = gwave; v < N_NODES; v += nwaves) {
        float f = feat[(long)v * DIM + lane];
        float o = 0.f;
#pragma unroll
        for (int k = 0; k < DIM; ++k)
            o = fmaf(__shfl(f, k, 64), Ws[k * DIM + lane], o);
        g[(long)v * DIM + lane] = o;
    }
}

// ===========================================================================
// Pull: 2 independent node streams per wave, zero-padded coop edge fetch
// ===========================================================================

// Core: accumulate two nodes' edge lists (each deg<=64) with all gathers
// independent. Lanes >= cnt are zeroed in-register: shfl of them yields
// {src=0, w=0} -> gather of hot line 0 times 0.0 (no guards needed).
__device__ __forceinline__ void accum2(const float* __restrict__ G,
                                       const uint2* __restrict__ srt,
                                       int begA, int cntA, int begB, int cntB,
                                       int lane, float& accA, float& accB) {
    uint2 uA = make_uint2(0u, 0u), uB = make_uint2(0u, 0u);
    if (lane < cntA) uA = srt[begA + lane];
    if (lane < cntB) uB = srt[begB + lane];
    int kmax = cntA > cntB ? cntA : cntB;
    for (int k = 0; k < kmax; k += 4) {
        unsigned a0 = __shfl(uA.x, k + 0), a1 = __shfl(uA.x, k + 1);
        unsigned a2 = __shfl(uA.x, k + 2), a3 = __shfl(uA.x, k + 3);
        unsigned b0 = __shfl(uB.x, k + 0), b1 = __shfl(uB.x, k + 1);
        unsigned b2 = __shfl(uB.x, k + 2), b3 = __shfl(uB.x, k + 3);
        float wa0 = __uint_as_float(__shfl(uA.y, k + 0));
        float wa1 = __uint_as_float(__shfl(uA.y, k + 1));
        float wa2 = __uint_as_float(__shfl(uA.y, k + 2));
        float wa3 = __uint_as_float(__shfl(uA.y, k + 3));
        float wb0 = __uint_as_float(__shfl(uB.y, k + 0));
        float wb1 = __uint_as_float(__shfl(uB.y, k + 1));
        float wb2 = __uint_as_float(__shfl(uB.y, k + 2));
        float wb3 = __uint_as_float(__shfl(uB.y, k + 3));
        float fa0 = G[a0 * DIM + lane];
        float fa1 = G[a1 * DIM + lane];
        float fa2 = G[a2 * DIM + lane];
        float fa3 = G[a3 * DIM + lane];
        float fb0 = G[b0 * DIM + lane];
        float fb1 = G[b1 * DIM + lane];
        float fb2 = G[b2 * DIM + lane];
        float fb3 = G[b3 * DIM + lane];
        accA = fmaf(fa0, wa0, accA); accA = fmaf(fa1, wa1, accA);
        accA = fmaf(fa2, wa2, accA); accA = fmaf(fa3, wa3, accA);
        accB = fmaf(fb0, wb0, accB); accB = fmaf(fb1, wb1, accB);
        accB = fmaf(fb2, wb2, accB); accB = fmaf(fb3, wb3, accB);
    }
}

// Rare path: degree > 64.
__device__ __forceinline__ float accum_slow(const float* __restrict__ G,
                                            const uint2* __restrict__ srt,
                                            int beg, int end, int lane) {
    float acc = 0.f;
    for (int base = beg; base < end; base += 64) {
        int cnt = end - base; if (cnt > 64) cnt = 64;
        uint2 u = make_uint2(0u, 0u);
        if (lane < cnt) u = srt[base + lane];
        for (int k = 0; k < cnt; k += 4) {
            unsigned s0 = __shfl(u.x, k + 0), s1 = __shfl(u.x, k + 1);
            unsigned s2 = __shfl(u.x, k + 2), s3 = __shfl(u.x, k + 3);
            float w0 = __uint_as_float(__shfl(u.y, k + 0));
            float w1 = __uint_as_float(__shfl(u.y, k + 1));
            float w2 = __uint_as_float(__shfl(u.y, k + 2));
            float w3 = __uint_as_float(__shfl(u.y, k + 3));
            float f0 = G[s0 * DIM + lane];
            float f1 = G[s1 * DIM + lane];
            float f2 = G[s2 * DIM + lane];
            float f3 = G[s3 * DIM + lane];
            acc = fmaf(f0, w0, acc); acc = fmaf(f1, w1, acc);
            acc = fmaf(f2, w2, acc); acc = fmaf(f3, w3, acc);
        }
    }
    return acc;
}

// Linear-first pull: gather pre-multiplied g, add bias, done.
__global__ __launch_bounds__(256, 4) void pull2_pre_kernel(
        const float* __restrict__ g, const uint2* __restrict__ srt,
        const unsigned* __restrict__ off, const float* __restrict__ bias,
        float* __restrict__ out) {
    int tid = threadIdx.x, lane = tid & 63;
    float bv = bias[lane];
    int gwave = (int)((blockIdx.x * blockDim.x + tid) >> 6);
    int nwaves = (int)((gridDim.x * blockDim.x) >> 6);
    for (int v = gwave; v < N_NODES; v += 2 * nwaves) {
        int vB = v + nwaves;
        int begA = (int)off[v];
        int cntA = (int)off[v + 1] - begA;
        int begB = 0, cntB = 0;
        if (vB < N_NODES) { begB = (int)off[vB]; cntB = (int)off[vB + 1] - begB; }
        float accA = 0.f, accB = 0.f;
        if (cntA <= 64 && cntB <= 64) {
            accum2(g, srt, begA, cntA, begB, cntB, lane, accA, accB);
        } else {
            accA = accum_slow(g, srt, begA, begA + cntA, lane);
            if (vB < N_NODES) accB = accum_slow(g, srt, begB, begB + cntB, lane);
        }
        out[(long)v * DIM + lane] = accA + bv;
        if (vB < N_NODES) out[(long)vB * DIM + lane] = accB + bv;
    }
}

// Fallback when ws can't hold g: gather feat, in-wave linear epilogue.
__global__ __launch_bounds__(256) void pull2_post_kernel(
        const float* __restrict__ feat, const uint2* __restrict__ srt,
        const unsigned* __restrict__ off, const float* __restrict__ W,
        const float* __restrict__ bias, float* __restrict__ out) {
    __shared__ float2 Ws2[(DIM / 2) * DIM];
    __shared__ float bs[DIM];
    int tid = threadIdx.x;
    for (int i = tid; i < (DIM / 2) * DIM; i += 256) {
        int k2 = i >> 6, ln = i & 63;
        Ws2[i] = make_float2(W[(2 * k2) * DIM + ln], W[(2 * k2 + 1) * DIM + ln]);
    }
    if (tid < DIM) bs[tid] = bias[tid];
    __syncthreads();
    int lane = tid & 63;
    int gwave = (int)((blockIdx.x * blockDim.x + tid) >> 6);
    int nwaves = (int)((gridDim.x * blockDim.x) >> 6);
    for (int v = gwave; v < N_NODES; v += 2 * nwaves) {
        int vB = v + nwaves;
        int begA = (int)off[v];
        int cntA = (int)off[v + 1] - begA;
        int begB = 0, cntB = 0;
        if (vB < N_NODES) { begB = (int)off[vB]; cntB = (int)off[vB + 1] - begB; }
        float accA = 0.f, accB = 0.f;
        if (cntA <= 64 && cntB <= 64) {
            accum2(feat, srt, begA, cntA, begB, cntB, lane, accA, accB);
        } else {
            accA = accum_slow(feat, srt, begA, begA + cntA, lane);
            if (vB < N_NODES) accB = accum_slow(feat, srt, begB, begB + cntB, lane);
        }
        float oA = bs[lane], oB = bs[lane];
#pragma unroll
        for (int k2 = 0; k2 < DIM / 2; ++k2) {
            float2 wp = Ws2[k2 * DIM + lane];
            oA = fmaf(__shfl(accA, 2 * k2 + 0, 64), wp.x, oA);
            oA = fmaf(__shfl(accA, 2 * k2 + 1, 64), wp.y, oA);
            oB = fmaf(__shfl(accB, 2 * k2 + 0, 64), wp.x, oB);
            oB = fmaf(__shfl(accB, 2 * k2 + 1, 64), wp.y, oB);
        }
        out[(long)v * DIM + lane] = oA;
        if (vB < N_NODES) out[(long)vB * DIM + lane] = oB;
    }
}

// ===========================================================================
// Last-resort fallback (round-0 kernels)
// ===========================================================================

__global__ void zero_kernel(float4* __restrict__ p, int n4) {
    int stride = gridDim.x * blockDim.x;
    for (int i = blockIdx.x * blockDim.x + threadIdx.x; i < n4; i += stride)
        p[i] = float4{0.f, 0.f, 0.f, 0.f};
}

__global__ void scatter_kernel(const float* __restrict__ feat,
                               const float* __restrict__ edge_w,
                               const int* __restrict__ src,
                               const int* __restrict__ dst,
                               float* __restrict__ h, int n_edges) {
    int lane = threadIdx.x & 63;
    int wave = (int)((blockIdx.x * blockDim.x + threadIdx.x) >> 6);
    int total_waves = (int)((gridDim.x * blockDim.x) >> 6);
    for (int e = wave; e < n_edges; e += total_waves) {
        int s = src[e], d = dst[e];
        float v = feat[(long)s * DIM + lane] * edge_w[e];
        atomicAdd(&h[(long)d * DIM + lane], v);
    }
}

__global__ void linear_kernel(float* __restrict__ h, const float* __restrict__ W,
                              const float* __restrict__ bias, int n_nodes) {
    __shared__ float Ws[DIM * DIM];
    __shared__ float bs[DIM];
    for (int i = threadIdx.x; i < DIM * DIM; i += blockDim.x) Ws[i] = W[i];
    if (threadIdx.x < DIM) bs[threadIdx.x] = bias[threadIdx.x];
    __syncthreads();
    int lane = threadIdx.x & 63;
    int gwave = blockIdx.x * (blockDim.x >> 6) + (threadIdx.x >> 6);
    int total_waves = gridDim.x * (blockDim.x >> 6);
    for (int row = gwave; row < n_nodes; row += total_waves) {
        float hval = h[(long)row * DIM + lane];
        float acc = bs[lane];
#pragma unroll
        for (int k = 0; k < DIM; ++k)
            acc = fmaf(__shfl(hval, k, 64), Ws[k * DIM + lane], acc);
        h[(long)row * DIM + lane] = acc;
    }
}

// ===========================================================================
extern "C" void kernel_launch(void* const* d_in, const int* in_sizes, int n_in,
                              void* d_out, int out_size, void* d_ws, size_t ws_size,
                              hipStream_t stream) {
    const float* feat   = (const float*)d_in[0];
    const float* edge_w = (const float*)d_in[1];
    const int*   src    = (const int*)d_in[2];
    const int*   dst    = (const int*)d_in[3];
    const float* weight = (const float*)d_in[4];
    const float* bias   = (const float*)d_in[5];
    float* out = (float*)d_out;

    size_t g_sz    = (size_t)N_NODES * DIM * 4;
    size_t srt_sz  = (size_t)N_EDGES * 8;
    size_t meta_sz = (size_t)N_NODES * 4 + (size_t)(N_NODES + 1) * 4
                   + (size_t)N_NODES * 4 + 64 * 4;

    if (ws_size >= g_sz + srt_sz + meta_sz) {
        // Full path: ws = [g | srt | cnt | off | cursor | partials]
        float*    g        = (float*)d_ws;
        uint2*    srt      = (uint2*)((char*)d_ws + g_sz);
        unsigned* cnt      = (unsigned*)((char*)d_ws + g_sz + srt_sz);
        unsigned* off      = cnt + N_NODES;
        unsigned* cursor   = off + N_NODES + 1;
        unsigned* partials = cursor + N_NODES;

        zero_u32<<<(N_NODES + 255) / 256, 256, 0, stream>>>(cnt, N_NODES);
        hist_kernel<<<2048, 256, 0, stream>>>(dst, cnt);
        scan1_kernel<<<NSCAN, 1024, 0, stream>>>(cnt, off, partials);
        scan2_kernel<<<1, 64, 0, stream>>>(partials);
        scan3_kernel<<<(N_NODES + 256) / 256, 256, 0, stream>>>(off, partials, cursor);
        scatter_sort_kernel<<<2048, 256, 0, stream>>>(src, dst, edge_w, cursor, srt);
        gemm_g_kernel<<<2048, 256, 0, stream>>>(feat, weight, g);
        pull2_pre_kernel<<<2048, 256, 0, stream>>>(g, srt, off, bias, out);
    } else if (ws_size >= srt_sz + meta_sz) {
        // No room for g: gather feat, in-wave linear.
        uint2*    srt      = (uint2*)d_ws;
        unsigned* cnt      = (unsigned*)((char*)d_ws + srt_sz);
        unsigned* off      = cnt + N_NODES;
        unsigned* cursor   = off + N_NODES + 1;
        unsigned* partials = cursor + N_NODES;

        zero_u32<<<(N_NODES + 255) / 256, 256, 0, stream>>>(cnt, N_NODES);
        hist_kernel<<<2048, 256, 0, stream>>>(dst, cnt);
        scan1_kernel<<<NSCAN, 1024, 0, stream>>>(cnt, off, partials);
        scan2_kernel<<<1, 64, 0, stream>>>(partials);
        scan3_kernel<<<(N_NODES + 256) / 256, 256, 0, stream>>>(off, partials, cursor);
        scatter_sort_kernel<<<2048, 256, 0, stream>>>(src, dst, edge_w, cursor, srt);
        pull2_post_kernel<<<2048, 256, 0, stream>>>(feat, srt, off, weight, bias, out);
    } else {
        int n4 = N_NODES * DIM / 4;
        zero_kernel<<<2048, 256, 0, stream>>>((float4*)out, n4);
        scatter_kernel<<<2048, 256, 0, stream>>>(feat, edge_w, src, dst, out, N_EDGES);
        linear_kernel<<<2048, 256, 0, stream>>>(out, weight, bias, N_NODES);
    }
}

// Round 7
// 253.546 us; speedup vs baseline: 1.1452x; 1.1452x over previous
//
#include <hip/hip_runtime.h>

#define N_NODES 100000
#define N_EDGES 1600000
#define DIM 64

#define SCAN_BLK 2048
#define NSCAN ((N_NODES + 1 + SCAN_BLK - 1) / SCAN_BLK)   // 49 blocks

#define NSLICE 8
#define SLICE_NODES ((N_NODES + NSLICE - 1) / NSLICE)     // 12500 nodes/slice

// Padded-CSR capacity: every node's range rounded up to 4 edges.
#define SRT_CAP (N_EDGES + 4 * N_NODES)                   // 2.0M entries (16 MB)

// ===========================================================================
// Prologue
// ===========================================================================

__global__ void zero_u32(unsigned* __restrict__ p, int n) {
    int stride = gridDim.x * blockDim.x;
    for (int i = blockIdx.x * blockDim.x + threadIdx.x; i < n; i += stride)
        p[i] = 0u;
}

// XCD-sliced per-node histogram (slice-local counter lines).
__global__ void hist_kernel(const int* __restrict__ dst, unsigned* __restrict__ cnt) {
    int slice = blockIdx.x & (NSLICE - 1);
    int chunk = blockIdx.x >> 3;
    int nchunks = gridDim.x >> 3;
    int lo = slice * SLICE_NODES;
    int hi = lo + SLICE_NODES; if (hi > N_NODES) hi = N_NODES;
    int per = (N_EDGES + nchunks - 1) / nchunks;
    int e0 = chunk * per;
    int e1 = e0 + per; if (e1 > N_EDGES) e1 = N_EDGES;
    for (int e = e0 + threadIdx.x; e < e1; e += blockDim.x) {
        int d = dst[e];
        if (d >= lo && d < hi) atomicAdd(&cnt[d], 1u);
    }
}

// Block-local scan of PADDED counts ((cnt+3)&~3) -> exclusive offsets.
__global__ void scan1_kernel(const unsigned* __restrict__ cnt,
                             unsigned* __restrict__ off,
                             unsigned* __restrict__ partials) {
    __shared__ unsigned s[SCAN_BLK];
    int t = threadIdx.x;
    int base = blockIdx.x * SCAN_BLK;
    int i0 = base + t, i1 = base + t + 1024;
    unsigned c0 = (i0 < N_NODES) ? ((cnt[i0] + 3u) & ~3u) : 0u;
    unsigned c1 = (i1 < N_NODES) ? ((cnt[i1] + 3u) & ~3u) : 0u;
    s[t] = c0;
    s[t + 1024] = c1;
    __syncthreads();
    for (int o = 1; o < SCAN_BLK; o <<= 1) {
        unsigned a0 = s[t];
        unsigned a1 = s[t + 1024];
        unsigned b0 = (t >= o) ? s[t - o] : 0u;
        unsigned b1 = (t + 1024 >= o) ? s[t + 1024 - o] : 0u;
        __syncthreads();
        s[t] = a0 + b0;
        s[t + 1024] = a1 + b1;
        __syncthreads();
    }
    for (int i = t; i < SCAN_BLK; i += 1024) {
        int gg = base + i;
        if (gg <= N_NODES) off[gg] = (i == 0) ? 0u : s[i - 1];
    }
    if (t == 0) partials[blockIdx.x] = s[SCAN_BLK - 1];
}

// Wave-parallel exclusive scan of 49 block partials.
__global__ void scan2_kernel(unsigned* __restrict__ partials) {
    int t = threadIdx.x;   // 64 threads
    unsigned v = (t < NSCAN) ? partials[t] : 0u;
    unsigned orig = v;
    for (int o = 1; o < 64; o <<= 1) {
        unsigned n = __shfl_up(v, o, 64);
        if (t >= o) v += n;
    }
    if (t < NSCAN) partials[t] = v - orig;
}

__global__ void scan3_kernel(unsigned* __restrict__ off,
                             const unsigned* __restrict__ partials,
                             unsigned* __restrict__ cursor) {
    int i = blockIdx.x * blockDim.x + threadIdx.x;
    if (i <= N_NODES) {
        unsigned v = off[i] + partials[i / SCAN_BLK];
        off[i] = v;
        if (i < N_NODES) cursor[i] = v;
    }
}

// XCD-sliced scatter into padded-CSR order (pads stay zero from memset).
__global__ void scatter_sort_kernel(const int* __restrict__ src,
                                    const int* __restrict__ dst,
                                    const float* __restrict__ w,
                                    unsigned* __restrict__ cursor,
                                    uint2* __restrict__ srt) {
    int slice = blockIdx.x & (NSLICE - 1);
    int chunk = blockIdx.x >> 3;
    int nchunks = gridDim.x >> 3;
    int lo = slice * SLICE_NODES;
    int hi = lo + SLICE_NODES; if (hi > N_NODES) hi = N_NODES;
    int per = (N_EDGES + nchunks - 1) / nchunks;
    int e0 = chunk * per;
    int e1 = e0 + per; if (e1 > N_EDGES) e1 = N_EDGES;
    for (int e = e0 + threadIdx.x; e < e1; e += blockDim.x) {
        int d = dst[e];
        if (d >= lo && d < hi) {
            unsigned pos = atomicAdd(&cursor[d], 1u);
            srt[pos] = make_uint2((unsigned)src[e], __float_as_uint(w[e]));
        }
    }
}

// ===========================================================================
// g = feat @ W — LDS-tiled, broadcast ds_read_b128, W column in VGPRs.
// No shfl/bpermute anywhere.
// ===========================================================================
__global__ __launch_bounds__(256) void gemm_g_kernel(const float* __restrict__ feat,
                                                     const float* __restrict__ W,
                                                     float* __restrict__ g) {
    __shared__ float4 ft[64 * 16];   // 64 rows x 64 cols = 16 KB
    int tid = threadIdx.x, lane = tid & 63, wv = tid >> 6;

    float Wreg[DIM];                 // W[k][lane] for all k
#pragma unroll
    for (int k = 0; k < DIM; ++k) Wreg[k] = W[k * DIM + lane];

    const float4* feat4 = (const float4*)feat;
    for (int tile = blockIdx.x; tile * 64 < N_NODES; tile += gridDim.x) {
        int base = tile * 64;
        int nrows = N_NODES - base; if (nrows > 64) nrows = 64;
        __syncthreads();
        for (int i = tid; i < 64 * 16; i += 256) {
            int r = i >> 4;
            ft[i] = (r < nrows) ? feat4[(size_t)(base + r) * 16 + (i & 15)]
                                : float4{0.f, 0.f, 0.f, 0.f};
        }
        __syncthreads();
        for (int r = wv; r < nrows; r += 4) {
            float acc = 0.f;
#pragma unroll
            for (int k4 = 0; k4 < 16; ++k4) {
                float4 f = ft[r * 16 + k4];   // uniform -> LDS broadcast
                acc = fmaf(f.x, Wreg[4 * k4 + 0], acc);
                acc = fmaf(f.y, Wreg[4 * k4 + 1], acc);
                acc = fmaf(f.z, Wreg[4 * k4 + 2], acc);
                acc = fmaf(f.w, Wreg[4 * k4 + 3], acc);
            }
            g[(size_t)(base + r) * DIM + lane] = acc;
        }
    }
}

// ===========================================================================
// Pull with scalar (SMEM) edge loads: edge records are wave-uniform; bases
// derived via readfirstlane so the compiler can emit s_load. Ranges padded
// to x4 with zeroed entries -> no guards, w=0 kills pad contributions.
// ===========================================================================
__global__ __launch_bounds__(256) void pull_scalar_kernel(
        const float* __restrict__ g, const uint2* __restrict__ srt,
        const unsigned* __restrict__ off, const float* __restrict__ bias,
        float* __restrict__ out) {
    int tid = threadIdx.x, lane = tid & 63;
    float bv = bias[lane];
    int gw = (int)((blockIdx.x * blockDim.x + tid) >> 6);
    int nw = (int)((gridDim.x * blockDim.x) >> 6);

    for (int v = gw; v < N_NODES; v += 2 * nw) {
        int vB = v + nw;
        int bA = (int)__builtin_amdgcn_readfirstlane((int)off[v]);
        int cA = (int)__builtin_amdgcn_readfirstlane((int)off[v + 1]) - bA;
        int bB = 0, cB = 0;
        if (vB < N_NODES) {
            bB = (int)__builtin_amdgcn_readfirstlane((int)off[vB]);
            cB = (int)__builtin_amdgcn_readfirstlane((int)off[vB + 1]) - bB;
        }
        float accA = 0.f, accB = 0.f;
        int kmax = cA > cB ? cA : cB;
        for (int k = 0; k < kmax; k += 4) {
            if (k < cA) {
                uint2 e0 = srt[bA + k + 0];
                uint2 e1 = srt[bA + k + 1];
                uint2 e2 = srt[bA + k + 2];
                uint2 e3 = srt[bA + k + 3];
                float f0 = g[e0.x * DIM + lane];
                float f1 = g[e1.x * DIM + lane];
                float f2 = g[e2.x * DIM + lane];
                float f3 = g[e3.x * DIM + lane];
                accA = fmaf(f0, __uint_as_float(e0.y), accA);
                accA = fmaf(f1, __uint_as_float(e1.y), accA);
                accA = fmaf(f2, __uint_as_float(e2.y), accA);
                accA = fmaf(f3, __uint_as_float(e3.y), accA);
            }
            if (k < cB) {
                uint2 e0 = srt[bB + k + 0];
                uint2 e1 = srt[bB + k + 1];
                uint2 e2 = srt[bB + k + 2];
                uint2 e3 = srt[bB + k + 3];
                float f0 = g[e0.x * DIM + lane];
                float f1 = g[e1.x * DIM + lane];
                float f2 = g[e2.x * DIM + lane];
                float f3 = g[e3.x * DIM + lane];
                accB = fmaf(f0, __uint_as_float(e0.y), accB);
                accB = fmaf(f1, __uint_as_float(e1.y), accB);
                accB = fmaf(f2, __uint_as_float(e2.y), accB);
                accB = fmaf(f3, __uint_as_float(e3.y), accB);
            }
        }
        out[(size_t)v * DIM + lane] = accA + bv;
        if (vB < N_NODES) out[(size_t)vB * DIM + lane] = accB + bv;
    }
}

// ===========================================================================
// Path-2 fallback: gather feat, in-wave shfl linear (works on padded CSR).
// ===========================================================================
__device__ __forceinline__ float accum_any(const float* __restrict__ G,
                                           const uint2* __restrict__ srt,
                                           int beg, int end, int lane) {
    float acc = 0.f;
    for (int base = beg; base < end; base += 64) {
        int cnt = end - base; if (cnt > 64) cnt = 64;
        uint2 u = make_uint2(0u, 0u);
        if (lane < cnt) u = srt[base + lane];
        for (int k = 0; k < cnt; k += 4) {
            unsigned s0 = __shfl(u.x, k + 0), s1 = __shfl(u.x, k + 1);
            unsigned s2 = __shfl(u.x, k + 2), s3 = __shfl(u.x, k + 3);
            float w0 = __uint_as_float(__shfl(u.y, k + 0));
            float w1 = __uint_as_float(__shfl(u.y, k + 1));
            float w2 = __uint_as_float(__shfl(u.y, k + 2));
            float w3 = __uint_as_float(__shfl(u.y, k + 3));
            float f0 = G[s0 * DIM + lane];
            float f1 = G[s1 * DIM + lane];
            float f2 = G[s2 * DIM + lane];
            float f3 = G[s3 * DIM + lane];
            acc = fmaf(f0, w0, acc); acc = fmaf(f1, w1, acc);
            acc = fmaf(f2, w2, acc); acc = fmaf(f3, w3, acc);
        }
    }
    return acc;
}

__global__ __launch_bounds__(256) void pull2_post_kernel(
        const float* __restrict__ feat, const uint2* __restrict__ srt,
        const unsigned* __restrict__ off, const float* __restrict__ W,
        const float* __restrict__ bias, float* __restrict__ out) {
    __shared__ float2 Ws2[(DIM / 2) * DIM];
    __shared__ float bs[DIM];
    int tid = threadIdx.x;
    for (int i = tid; i < (DIM / 2) * DIM; i += 256) {
        int k2 = i >> 6, ln = i & 63;
        Ws2[i] = make_float2(W[(2 * k2) * DIM + ln], W[(2 * k2 + 1) * DIM + ln]);
    }
    if (tid < DIM) bs[tid] = bias[tid];
    __syncthreads();
    int lane = tid & 63;
    int gwave = (int)((blockIdx.x * blockDim.x + tid) >> 6);
    int nwaves = (int)((gridDim.x * blockDim.x) >> 6);
    for (int v = gwave; v < N_NODES; v += nwaves) {
        float acc = accum_any(feat, srt, (int)off[v], (int)off[v + 1], lane);
        float o = bs[lane];
#pragma unroll
        for (int k2 = 0; k2 < DIM / 2; ++k2) {
            float2 wp = Ws2[k2 * DIM + lane];
            o = fmaf(__shfl(acc, 2 * k2 + 0, 64), wp.x, o);
            o = fmaf(__shfl(acc, 2 * k2 + 1, 64), wp.y, o);
        }
        out[(long)v * DIM + lane] = o;
    }
}

// ===========================================================================
// Last-resort fallback (round-0 kernels)
// ===========================================================================

__global__ void zero_kernel(float4* __restrict__ p, int n4) {
    int stride = gridDim.x * blockDim.x;
    for (int i = blockIdx.x * blockDim.x + threadIdx.x; i < n4; i += stride)
        p[i] = float4{0.f, 0.f, 0.f, 0.f};
}

__global__ void scatter_kernel(const float* __restrict__ feat,
                               const float* __restrict__ edge_w,
                               const int* __restrict__ src,
                               const int* __restrict__ dst,
                               float* __restrict__ h, int n_edges) {
    int lane = threadIdx.x & 63;
    int wave = (int)((blockIdx.x * blockDim.x + threadIdx.x) >> 6);
    int total_waves = (int)((gridDim.x * blockDim.x) >> 6);
    for (int e = wave; e < n_edges; e += total_waves) {
        int s = src[e], d = dst[e];
        float v = feat[(long)s * DIM + lane] * edge_w[e];
        atomicAdd(&h[(long)d * DIM + lane], v);
    }
}

__global__ void linear_kernel(float* __restrict__ h, const float* __restrict__ W,
                              const float* __restrict__ bias, int n_nodes) {
    __shared__ float Ws[DIM * DIM];
    __shared__ float bs[DIM];
    for (int i = threadIdx.x; i < DIM * DIM; i += blockDim.x) Ws[i] = W[i];
    if (threadIdx.x < DIM) bs[threadIdx.x] = bias[threadIdx.x];
    __syncthreads();
    int lane = threadIdx.x & 63;
    int gwave = blockIdx.x * (blockDim.x >> 6) + (threadIdx.x >> 6);
    int total_waves = gridDim.x * (blockDim.x >> 6);
    for (int row = gwave; row < n_nodes; row += total_waves) {
        float hval = h[(long)row * DIM + lane];
        float acc = bs[lane];
#pragma unroll
        for (int k = 0; k < DIM; ++k)
            acc = fmaf(__shfl(hval, k, 64), Ws[k * DIM + lane], acc);
        h[(long)row * DIM + lane] = acc;
    }
}

// ===========================================================================
extern "C" void kernel_launch(void* const* d_in, const int* in_sizes, int n_in,
                              void* d_out, int out_size, void* d_ws, size_t ws_size,
                              hipStream_t stream) {
    const float* feat   = (const float*)d_in[0];
    const float* edge_w = (const float*)d_in[1];
    const int*   src    = (const int*)d_in[2];
    const int*   dst    = (const int*)d_in[3];
    const float* weight = (const float*)d_in[4];
    const float* bias   = (const float*)d_in[5];
    float* out = (float*)d_out;

    size_t g_sz    = (size_t)N_NODES * DIM * 4;              // 25.6 MB
    size_t srt_sz  = (size_t)SRT_CAP * 8;                    // 16.0 MB
    size_t meta_sz = (size_t)N_NODES * 4 + (size_t)(N_NODES + 1) * 4
                   + (size_t)N_NODES * 4 + 64 * 4;           // ~1.2 MB

    if (ws_size >= g_sz + srt_sz + meta_sz) {
        float*    g        = (float*)d_ws;
        uint2*    srt      = (uint2*)((char*)d_ws + g_sz);
        unsigned* cnt      = (unsigned*)((char*)d_ws + g_sz + srt_sz);
        unsigned* off      = cnt + N_NODES;
        unsigned* cursor   = off + N_NODES + 1;
        unsigned* partials = cursor + N_NODES;

        zero_u32<<<(N_NODES + 255) / 256, 256, 0, stream>>>(cnt, N_NODES);
        zero_u32<<<2048, 256, 0, stream>>>((unsigned*)srt, SRT_CAP * 2);
        hist_kernel<<<2048, 256, 0, stream>>>(dst, cnt);
        scan1_kernel<<<NSCAN, 1024, 0, stream>>>(cnt, off, partials);
        scan2_kernel<<<1, 64, 0, stream>>>(partials);
        scan3_kernel<<<(N_NODES + 256) / 256, 256, 0, stream>>>(off, partials, cursor);
        scatter_sort_kernel<<<2048, 256, 0, stream>>>(src, dst, edge_w, cursor, srt);
        gemm_g_kernel<<<1563, 256, 0, stream>>>(feat, weight, g);
        pull_scalar_kernel<<<2048, 256, 0, stream>>>(g, srt, off, bias, out);
    } else if (ws_size >= srt_sz + meta_sz) {
        uint2*    srt      = (uint2*)d_ws;
        unsigned* cnt      = (unsigned*)((char*)d_ws + srt_sz);
        unsigned* off      = cnt + N_NODES;
        unsigned* cursor   = off + N_NODES + 1;
        unsigned* partials = cursor + N_NODES;

        zero_u32<<<(N_NODES + 255) / 256, 256, 0, stream>>>(cnt, N_NODES);
        zero_u32<<<2048, 256, 0, stream>>>((unsigned*)srt, SRT_CAP * 2);
        hist_kernel<<<2048, 256, 0, stream>>>(dst, cnt);
        scan1_kernel<<<NSCAN, 1024, 0, stream>>>(cnt, off, partials);
        scan2_kernel<<<1, 64, 0, stream>>>(partials);
        scan3_kernel<<<(N_NODES + 256) / 256, 256, 0, stream>>>(off, partials, cursor);
        scatter_sort_kernel<<<2048, 256, 0, stream>>>(src, dst, edge_w, cursor, srt);
        pull2_post_kernel<<<2048, 256, 0, stream>>>(feat, srt, off, weight, bias, out);
    } else {
        int n4 = N_NODES * DIM / 4;
        zero_kernel<<<2048, 256, 0, stream>>>((float4*)out, n4);
        scatter_kernel<<<2048, 256, 0, stream>>>(feat, edge_w, src, dst, out, N_EDGES);
        linear_kernel<<<2048, 256, 0, stream>>>(out, weight, bias, N_NODES);
    }
}

// Round 8
// 232.886 us; speedup vs baseline: 1.2468x; 1.0887x over previous
//
#include <hip/hip_runtime.h>

#define N_NODES 100000
#define N_EDGES 1600000
#define DIM 64

#define NSLICE 8
#define SLICE_NODES ((N_NODES + NSLICE - 1) / NSLICE)     // 12500 nodes/slice

#define CAP 32                     // fixed slots per node (deg ~ Poisson(16))
#define OVF_CAP 65536

// ---- legacy exact-CSR path constants (fallback) ----
#define SCAN_BLK 2048
#define NSCAN ((N_NODES + 1 + SCAN_BLK - 1) / SCAN_BLK)
#define SRT_CAP (N_EDGES + 4 * N_NODES)

// ===========================================================================
// Path A: fixed-capacity bucket sort (no hist, no scan)
// ===========================================================================

__global__ void zero_u32(unsigned* __restrict__ p, int n) {
    int stride = gridDim.x * blockDim.x;
    for (int i = blockIdx.x * blockDim.x + threadIdx.x; i < n; i += stride)
        p[i] = 0u;
}

// XCD-sliced fixed-cap scatter. Streaming inputs use nontemporal loads so the
// slice-local srt/cursor lines stay resident in the XCD's L2.
__global__ void scatter_fixed_kernel(const int* __restrict__ src,
                                     const int* __restrict__ dst,
                                     const float* __restrict__ w,
                                     unsigned* __restrict__ cursor,
                                     uint2* __restrict__ srt,
                                     unsigned* __restrict__ ovf_cnt,
                                     uint4* __restrict__ ovf) {
    int slice = blockIdx.x & (NSLICE - 1);
    int chunk = blockIdx.x >> 3;
    int nchunks = gridDim.x >> 3;
    int lo = slice * SLICE_NODES;
    int hi = lo + SLICE_NODES; if (hi > N_NODES) hi = N_NODES;
    int per = (N_EDGES + nchunks - 1) / nchunks;
    int e0 = chunk * per;
    int e1 = e0 + per; if (e1 > N_EDGES) e1 = N_EDGES;
    for (int e = e0 + threadIdx.x; e < e1; e += blockDim.x) {
        int d = __builtin_nontemporal_load(&dst[e]);
        if (d >= lo && d < hi) {
            int s = __builtin_nontemporal_load(&src[e]);
            float ww = __builtin_nontemporal_load(&w[e]);
            unsigned pos = atomicAdd(&cursor[d], 1u);
            if (pos < CAP) {
                srt[(size_t)d * CAP + pos] =
                    make_uint2((unsigned)s, __float_as_uint(ww));
            } else {
                unsigned op = atomicAdd(ovf_cnt, 1u);
                if (op < OVF_CAP)
                    ovf[op] = make_uint4((unsigned)d, (unsigned)s,
                                         __float_as_uint(ww), 0u);
            }
        }
    }
}

// g = feat @ W — LDS-tiled, broadcast ds_read_b128, W column in VGPRs.
__global__ __launch_bounds__(256) void gemm_g_kernel(const float* __restrict__ feat,
                                                     const float* __restrict__ W,
                                                     float* __restrict__ g) {
    __shared__ float4 ft[64 * 16];   // 64 rows x 64 cols = 16 KB
    int tid = threadIdx.x, lane = tid & 63, wv = tid >> 6;

    float Wreg[DIM];
#pragma unroll
    for (int k = 0; k < DIM; ++k) Wreg[k] = W[k * DIM + lane];

    const float4* feat4 = (const float4*)feat;
    for (int tile = blockIdx.x; tile * 64 < N_NODES; tile += gridDim.x) {
        int base = tile * 64;
        int nrows = N_NODES - base; if (nrows > 64) nrows = 64;
        __syncthreads();
        for (int i = tid; i < 64 * 16; i += 256) {
            int r = i >> 4;
            ft[i] = (r < nrows) ? feat4[(size_t)(base + r) * 16 + (i & 15)]
                                : float4{0.f, 0.f, 0.f, 0.f};
        }
        __syncthreads();
        for (int r = wv; r < nrows; r += 4) {
            float acc = 0.f;
#pragma unroll
            for (int k4 = 0; k4 < 16; ++k4) {
                float4 f = ft[r * 16 + k4];
                acc = fmaf(f.x, Wreg[4 * k4 + 0], acc);
                acc = fmaf(f.y, Wreg[4 * k4 + 1], acc);
                acc = fmaf(f.z, Wreg[4 * k4 + 2], acc);
                acc = fmaf(f.w, Wreg[4 * k4 + 3], acc);
            }
            g[(size_t)(base + r) * DIM + lane] = acc;
        }
    }
}

// Pull over fixed-cap buckets: true count from cursor; ragged tail handled by
// SCALAR selects (src->0, w->0) so all 8 gathers issue unconditionally.
__global__ __launch_bounds__(256) void pull_fixed_kernel(
        const float* __restrict__ g, const uint2* __restrict__ srt,
        const unsigned* __restrict__ cursor, const float* __restrict__ bias,
        float* __restrict__ out) {
    int tid = threadIdx.x, lane = tid & 63;
    float bv = bias[lane];
    int gw = (int)((blockIdx.x * blockDim.x + tid) >> 6);
    int nw = (int)((gridDim.x * blockDim.x) >> 6);

    for (int v = gw; v < N_NODES; v += 2 * nw) {
        int vB = v + nw;
        int cA = (int)__builtin_amdgcn_readfirstlane((int)cursor[v]);
        cA = cA < CAP ? cA : CAP;
        int cB = 0;
        if (vB < N_NODES) {
            cB = (int)__builtin_amdgcn_readfirstlane((int)cursor[vB]);
            cB = cB < CAP ? cB : CAP;
        }
        int vBc = vB < N_NODES ? vB : N_NODES - 1;
        const uint2* pA = srt + (size_t)v * CAP;
        const uint2* pB = srt + (size_t)vBc * CAP;

        float accA = 0.f, accB = 0.f;
        int kmax = cA > cB ? cA : cB;
        for (int k = 0; k < kmax; k += 4) {
#pragma unroll
            for (int j = 0; j < 4; ++j) {
                uint2 eA = pA[k + j];                       // always in-bounds
                unsigned sA = (k + j < cA) ? eA.x : 0u;     // scalar selects
                float    wA = (k + j < cA) ? __uint_as_float(eA.y) : 0.f;
                accA = fmaf(g[(size_t)sA * DIM + lane], wA, accA);
            }
#pragma unroll
            for (int j = 0; j < 4; ++j) {
                uint2 eB = pB[k + j];
                unsigned sB = (k + j < cB) ? eB.x : 0u;
                float    wB = (k + j < cB) ? __uint_as_float(eB.y) : 0.f;
                accB = fmaf(g[(size_t)sB * DIM + lane], wB, accB);
            }
        }
        __builtin_nontemporal_store(accA + bv, &out[(size_t)v * DIM + lane]);
        if (vB < N_NODES)
            __builtin_nontemporal_store(accB + bv, &out[(size_t)vB * DIM + lane]);
    }
}

// Apply rare overflow edges (pos >= CAP) after pull wrote out.
__global__ void cleanup_ovf_kernel(const float* __restrict__ g,
                                   const uint4* __restrict__ ovf,
                                   const unsigned* __restrict__ ovf_cnt,
                                   float* __restrict__ out) {
    int lane = threadIdx.x & 63;
    int wv = (int)((blockIdx.x * blockDim.x + threadIdx.x) >> 6);
    int nwv = (int)((gridDim.x * blockDim.x) >> 6);
    unsigned nraw = *ovf_cnt;
    int n = (int)(nraw < (unsigned)OVF_CAP ? nraw : (unsigned)OVF_CAP);
    for (int i = wv; i < n; i += nwv) {
        uint4 t = ovf[i];
        atomicAdd(&out[(size_t)t.x * DIM + lane],
                  g[(size_t)t.y * DIM + lane] * __uint_as_float(t.z));
    }
}

// ===========================================================================
// Path B (fallback): R7 exact padded-CSR pipeline
// ===========================================================================

__global__ void hist_kernel(const int* __restrict__ dst, unsigned* __restrict__ cnt) {
    int slice = blockIdx.x & (NSLICE - 1);
    int chunk = blockIdx.x >> 3;
    int nchunks = gridDim.x >> 3;
    int lo = slice * SLICE_NODES;
    int hi = lo + SLICE_NODES; if (hi > N_NODES) hi = N_NODES;
    int per = (N_EDGES + nchunks - 1) / nchunks;
    int e0 = chunk * per;
    int e1 = e0 + per; if (e1 > N_EDGES) e1 = N_EDGES;
    for (int e = e0 + threadIdx.x; e < e1; e += blockDim.x) {
        int d = dst[e];
        if (d >= lo && d < hi) atomicAdd(&cnt[d], 1u);
    }
}

__global__ void scan1_kernel(const unsigned* __restrict__ cnt,
                             unsigned* __restrict__ off,
                             unsigned* __restrict__ partials) {
    __shared__ unsigned s[SCAN_BLK];
    int t = threadIdx.x;
    int base = blockIdx.x * SCAN_BLK;
    int i0 = base + t, i1 = base + t + 1024;
    unsigned c0 = (i0 < N_NODES) ? ((cnt[i0] + 3u) & ~3u) : 0u;
    unsigned c1 = (i1 < N_NODES) ? ((cnt[i1] + 3u) & ~3u) : 0u;
    s[t] = c0;
    s[t + 1024] = c1;
    __syncthreads();
    for (int o = 1; o < SCAN_BLK; o <<= 1) {
        unsigned a0 = s[t];
        unsigned a1 = s[t + 1024];
        unsigned b0 = (t >= o) ? s[t - o] : 0u;
        unsigned b1 = (t + 1024 >= o) ? s[t + 1024 - o] : 0u;
        __syncthreads();
        s[t] = a0 + b0;
        s[t + 1024] = a1 + b1;
        __syncthreads();
    }
    for (int i = t; i < SCAN_BLK; i += 1024) {
        int gg = base + i;
        if (gg <= N_NODES) off[gg] = (i == 0) ? 0u : s[i - 1];
    }
    if (t == 0) partials[blockIdx.x] = s[SCAN_BLK - 1];
}

__global__ void scan2_kernel(unsigned* __restrict__ partials) {
    int t = threadIdx.x;
    unsigned v = (t < NSCAN) ? partials[t] : 0u;
    unsigned orig = v;
    for (int o = 1; o < 64; o <<= 1) {
        unsigned n = __shfl_up(v, o, 64);
        if (t >= o) v += n;
    }
    if (t < NSCAN) partials[t] = v - orig;
}

__global__ void scan3_kernel(unsigned* __restrict__ off,
                             const unsigned* __restrict__ partials,
                             unsigned* __restrict__ cursor) {
    int i = blockIdx.x * blockDim.x + threadIdx.x;
    if (i <= N_NODES) {
        unsigned v = off[i] + partials[i / SCAN_BLK];
        off[i] = v;
        if (i < N_NODES) cursor[i] = v;
    }
}

__global__ void scatter_sort_kernel(const int* __restrict__ src,
                                    const int* __restrict__ dst,
                                    const float* __restrict__ w,
                                    unsigned* __restrict__ cursor,
                                    uint2* __restrict__ srt) {
    int slice = blockIdx.x & (NSLICE - 1);
    int chunk = blockIdx.x >> 3;
    int nchunks = gridDim.x >> 3;
    int lo = slice * SLICE_NODES;
    int hi = lo + SLICE_NODES; if (hi > N_NODES) hi = N_NODES;
    int per = (N_EDGES + nchunks - 1) / nchunks;
    int e0 = chunk * per;
    int e1 = e0 + per; if (e1 > N_EDGES) e1 = N_EDGES;
    for (int e = e0 + threadIdx.x; e < e1; e += blockDim.x) {
        int d = dst[e];
        if (d >= lo && d < hi) {
            unsigned pos = atomicAdd(&cursor[d], 1u);
            srt[pos] = make_uint2((unsigned)src[e], __float_as_uint(w[e]));
        }
    }
}

__global__ __launch_bounds__(256) void pull_scalar_kernel(
        const float* __restrict__ g, const uint2* __restrict__ srt,
        const unsigned* __restrict__ off, const float* __restrict__ bias,
        float* __restrict__ out) {
    int tid = threadIdx.x, lane = tid & 63;
    float bv = bias[lane];
    int gw = (int)((blockIdx.x * blockDim.x + tid) >> 6);
    int nw = (int)((gridDim.x * blockDim.x) >> 6);

    for (int v = gw; v < N_NODES; v += 2 * nw) {
        int vB = v + nw;
        int bA = (int)__builtin_amdgcn_readfirstlane((int)off[v]);
        int cA = (int)__builtin_amdgcn_readfirstlane((int)off[v + 1]) - bA;
        int bB = 0, cB = 0;
        if (vB < N_NODES) {
            bB = (int)__builtin_amdgcn_readfirstlane((int)off[vB]);
            cB = (int)__builtin_amdgcn_readfirstlane((int)off[vB + 1]) - bB;
        }
        float accA = 0.f, accB = 0.f;
        int kmax = cA > cB ? cA : cB;
        for (int k = 0; k < kmax; k += 4) {
            if (k < cA) {
                uint2 e0 = srt[bA + k + 0];
                uint2 e1 = srt[bA + k + 1];
                uint2 e2 = srt[bA + k + 2];
                uint2 e3 = srt[bA + k + 3];
                accA = fmaf(g[e0.x * DIM + lane], __uint_as_float(e0.y), accA);
                accA = fmaf(g[e1.x * DIM + lane], __uint_as_float(e1.y), accA);
                accA = fmaf(g[e2.x * DIM + lane], __uint_as_float(e2.y), accA);
                accA = fmaf(g[e3.x * DIM + lane], __uint_as_float(e3.y), accA);
            }
            if (k < cB) {
                uint2 e0 = srt[bB + k + 0];
                uint2 e1 = srt[bB + k + 1];
                uint2 e2 = srt[bB + k + 2];
                uint2 e3 = srt[bB + k + 3];
                accB = fmaf(g[e0.x * DIM + lane], __uint_as_float(e0.y), accB);
                accB = fmaf(g[e1.x * DIM + lane], __uint_as_float(e1.y), accB);
                accB = fmaf(g[e2.x * DIM + lane], __uint_as_float(e2.y), accB);
                accB = fmaf(g[e3.x * DIM + lane], __uint_as_float(e3.y), accB);
            }
        }
        out[(size_t)v * DIM + lane] = accA + bv;
        if (vB < N_NODES) out[(size_t)vB * DIM + lane] = accB + bv;
    }
}

// ===========================================================================
extern "C" void kernel_launch(void* const* d_in, const int* in_sizes, int n_in,
                              void* d_out, int out_size, void* d_ws, size_t ws_size,
                              hipStream_t stream) {
    const float* feat   = (const float*)d_in[0];
    const float* edge_w = (const float*)d_in[1];
    const int*   src    = (const int*)d_in[2];
    const int*   dst    = (const int*)d_in[3];
    const float* weight = (const float*)d_in[4];
    const float* bias   = (const float*)d_in[5];
    float* out = (float*)d_out;

    size_t g_sz     = (size_t)N_NODES * DIM * 4;             // 25.6 MB
    size_t srt32_sz = (size_t)N_NODES * CAP * 8;             // 25.6 MB
    size_t curA_sz  = (size_t)(N_NODES + 4) * 4;             // cursor + ovf_cnt + pad
    size_t ovf_sz   = (size_t)OVF_CAP * 16;                  // 1 MB
    size_t neededA  = g_sz + srt32_sz + curA_sz + ovf_sz;    // ~52.7 MB

    size_t srtB_sz  = (size_t)SRT_CAP * 8;                   // 16.0 MB
    size_t metaB_sz = (size_t)N_NODES * 4 + (size_t)(N_NODES + 1) * 4
                    + (size_t)N_NODES * 4 + 64 * 4;
    size_t neededB  = g_sz + srtB_sz + metaB_sz;             // ~42.8 MB

    if (ws_size >= neededA) {
        float*    g       = (float*)d_ws;
        uint2*    srt     = (uint2*)((char*)d_ws + g_sz);
        unsigned* cursor  = (unsigned*)((char*)d_ws + g_sz + srt32_sz);
        unsigned* ovf_cnt = cursor + N_NODES;
        uint4*    ovf     = (uint4*)((char*)d_ws + g_sz + srt32_sz + curA_sz);

        zero_u32<<<(N_NODES + 256) / 256, 256, 0, stream>>>(cursor, N_NODES + 1);
        scatter_fixed_kernel<<<2048, 256, 0, stream>>>(src, dst, edge_w,
                                                       cursor, srt, ovf_cnt, ovf);
        gemm_g_kernel<<<1563, 256, 0, stream>>>(feat, weight, g);
        pull_fixed_kernel<<<2048, 256, 0, stream>>>(g, srt, cursor, bias, out);
        cleanup_ovf_kernel<<<64, 256, 0, stream>>>(g, ovf, ovf_cnt, out);
    } else {
        // R7 exact padded-CSR path (proven)
        float*    g        = (float*)d_ws;
        uint2*    srt      = (uint2*)((char*)d_ws + g_sz);
        unsigned* cnt      = (unsigned*)((char*)d_ws + g_sz + srtB_sz);
        unsigned* off      = cnt + N_NODES;
        unsigned* cursor   = off + N_NODES + 1;
        unsigned* partials = cursor + N_NODES;

        zero_u32<<<(N_NODES + 255) / 256, 256, 0, stream>>>(cnt, N_NODES);
        zero_u32<<<2048, 256, 0, stream>>>((unsigned*)srt, SRT_CAP * 2);
        hist_kernel<<<2048, 256, 0, stream>>>(dst, cnt);
        scan1_kernel<<<NSCAN, 1024, 0, stream>>>(cnt, off, partials);
        scan2_kernel<<<1, 64, 0, stream>>>(partials);
        scan3_kernel<<<(N_NODES + 256) / 256, 256, 0, stream>>>(off, partials, cursor);
        scatter_sort_kernel<<<2048, 256, 0, stream>>>(src, dst, edge_w, cursor, srt);
        gemm_g_kernel<<<1563, 256, 0, stream>>>(feat, weight, g);
        pull_scalar_kernel<<<2048, 256, 0, stream>>>(g, srt, off, bias, out);
    }
}